// Round 6
// baseline (113.985 us; speedup 1.0000x reference)
//
#include <hip/hip_runtime.h>
#include <hip/hip_bf16.h>

typedef float  f32x4  __attribute__((ext_vector_type(4)));
typedef short  bf16x8 __attribute__((ext_vector_type(8)));

#define NT      16384              // BATCH*SEQ tokens
#define NBLOCK  256                // 1 block/CU (160KB LDS), 4 waves each
#define WPB     4
#define NSTREAM (NBLOCK * WPB)     // 1024 streams
#define TPS     (NT / NSTREAM)     // 16 tokens per wave, strided by NSTREAM

__device__ __forceinline__ short f2bf(float x) {
  // HW conversion: compiler emits v_cvt_pk_bf16_f32 (RNE).
  return (short)__builtin_bit_cast(unsigned short, __float2bfloat16(x));
}

__device__ __forceinline__ void gload16(const float* gp, float* lp) {
  __builtin_amdgcn_global_load_lds((const __attribute__((address_space(1))) void*)gp,
                                   (__attribute__((address_space(3))) void*)lp,
                                   16, 0, 0);
}

__device__ __forceinline__ unsigned ldsaddr(const void* p) {
  return (unsigned)(uintptr_t)(const __attribute__((address_space(3))) void*)p;
}

// Stage one token's X (64x64 fp32 = 16KB) via 16 x global_load_lds(16B).
// LDS dest linear; XOR swizzle (16B chunks, chunk ^= row&7) applied to the
// GLOBAL source so fragment ds_read_b128s are conflict-free (R1: 0 conflicts).
__device__ __forceinline__ void stage(float* XB, const float* gbase, int lane) {
#pragma unroll
  for (int q = 0; q < 16; ++q) {
    const int i = q * 4 + (lane >> 4);
    const float* gp = gbase + i * 64 + (((lane & 15) ^ (i & 7)) << 2);
    gload16(gp, XB + q * 256);
  }
}

__global__ __launch_bounds__(256, 1)
void kron_kernel(const float* __restrict__ x,
                 const float* __restrict__ A,
                 const float* __restrict__ Bm,
                 const float* __restrict__ bias,
                 float* __restrict__ out) {
  __shared__ float  xh[WPB][2][4096];  // 128KB: per-wave token double-buffers
  __shared__ bf16x8 AT[1024];          // 16KB  [s*8+ot*2+c][lane], sigma2 baked
  __shared__ bf16x8 BT[1024];          // 16KB  [s*8+pt*2+jc][lane], sigma1

  const int tid  = threadIdx.x;
  const int lane = tid & 63;
  const int w    = tid >> 6;
  const int g    = lane >> 4;
  const int l15  = lane & 15;
  const int sid  = blockIdx.x * WPB + w;   // stream id in [0, NSTREAM)

  // ---- one-time: operand tables, built cooperatively (4 rows/wave/table) ----
#pragma unroll
  for (int t = 0; t < 4; ++t) {                  // A: idx = s*8 + ot*2 + c
    const int idx = w * 4 + t;
    const int s = idx >> 3, ot = (idx & 7) >> 1, c = idx & 1;
    const int o = ot * 16 + l15;
    bf16x8 v;
#pragma unroll
    for (int e = 0; e < 8; ++e) {
      const int i = c * 32 + 4 * g + (e & 3) + 16 * (e >> 2);   // sigma2
      v[e] = f2bf(A[s * 4096 + o * 64 + i]);
    }
    AT[idx * 64 + lane] = v;
  }
#pragma unroll
  for (int t = 0; t < 4; ++t) {                  // B: idx = s*8 + pt*2 + jc
    const int idx = w * 4 + t;
    const int s = idx >> 3, pt = (idx & 7) >> 1, jc = idx & 1;
    const int p = pt * 16 + l15;
    bf16x8 v;
#pragma unroll
    for (int e = 0; e < 8; ++e)
      v[e] = f2bf(Bm[s * 4096 + p * 64 + (jc * 32 + 8 * g + e)]); // sigma1
    BT[idx * 64 + lane] = v;
  }

  // ---- bias -> VGPRs (16 x f32x4); acc2 is initialized from these ----
  const int pcol = 4 * g;
  f32x4 bv[4][4];
#pragma unroll
  for (int pt = 0; pt < 4; ++pt)
#pragma unroll
    for (int ot = 0; ot < 4; ++ot)
      bv[pt][ot] = *(const f32x4*)(bias + (ot * 16 + l15) * 64 + pt * 16 + pcol);

  // Barrier drains vmcnt+lgkmcnt: clean queue before the counted-wait pipeline.
  __syncthreads();

  float* b0 = &xh[w][0][0];
  float* b1 = &xh[w][1][0];

  // ---- prologue: prefetch tokens 0,1 of this stream ----
  stage(b0, x + ((size_t)sid << 12), lane);
  stage(b1, x + ((size_t)(sid + NSTREAM) << 12), lane);

  for (int k = 0; k < TPS; ++k) {
    // Body k issue order: [wait][ds_reads][stage(k+2)][cvt+MFMA][stores(k)].
    // Queue at the wait (oldest->newest), steady state k in [2, TPS-2]:
    //   stage(k) | stores(k-2) | stage(k+1) | stores(k-1)  -> newer = 48.
    // k=0: only stage(1) newer (16). k=1: stage(2),stores(0) newer +stage(1)
    // -> 32. k=TPS-1: stage(TPS) skipped -> stores(TPS-3),stores(TPS-2) newer
    // + stage(TPS-1) -> 32.
    if (k == 0)                        asm volatile("s_waitcnt vmcnt(16)" ::: "memory");
    else if (k == 1 || k == TPS - 1)   asm volatile("s_waitcnt vmcnt(32)" ::: "memory");
    else                               asm volatile("s_waitcnt vmcnt(48)" ::: "memory");

    // ---- X fragment reads (inline asm: invisible to the waitcnt pass) ----
    const unsigned ba = ldsaddr((k & 1) ? b1 : b0);
    f32x4 r0[4][2], r1[4][2];
#pragma unroll
    for (int it = 0; it < 4; ++it) {
      const unsigned base = ba + (unsigned)(it * 16 + l15) * 256u;
      const unsigned m    = (unsigned)(l15 & 7);
#pragma unroll
      for (int jc = 0; jc < 2; ++jc) {
        const unsigned c0 = (unsigned)(8 * jc + 2 * g);
        asm volatile("ds_read_b128 %0, %1" : "=v"(r0[it][jc]) : "v"(base + ((c0 ^ m) << 4)) : "memory");
        asm volatile("ds_read_b128 %0, %1" : "=v"(r1[it][jc]) : "v"(base + (((c0 + 1u) ^ m) << 4)) : "memory");
      }
    }
    asm volatile("s_waitcnt lgkmcnt(0)" ::: "memory");
    __builtin_amdgcn_sched_barrier(0);

    // ---- prefetch token k+2 into the buffer just consumed (reads are done) ----
    if (k + 2 < TPS)
      stage((k & 1) ? b1 : b0,
            x + ((size_t)((k + 2) * NSTREAM + sid) << 12), lane);

    bf16x8 xf[4][2];
#pragma unroll
    for (int it = 0; it < 4; ++it)
#pragma unroll
      for (int jc = 0; jc < 2; ++jc) {
        bf16x8 t;
        t[0]=f2bf(r0[it][jc][0]); t[1]=f2bf(r0[it][jc][1]);
        t[2]=f2bf(r0[it][jc][2]); t[3]=f2bf(r0[it][jc][3]);
        t[4]=f2bf(r1[it][jc][0]); t[5]=f2bf(r1[it][jc][1]);
        t[6]=f2bf(r1[it][jc][2]); t[7]=f2bf(r1[it][jc][3]);
        xf[it][jc] = t;
      }

    // ---- acc2 = bias (folded init) ----
    f32x4 acc2[4][4];
#pragma unroll
    for (int pt = 0; pt < 4; ++pt)
#pragma unroll
      for (int ot = 0; ot < 4; ++ot)
        acc2[pt][ot] = bv[pt][ot];

#pragma unroll
    for (int s = 0; s < 2; ++s) {
      bf16x8 bfr[4][2];
#pragma unroll
      for (int pt = 0; pt < 4; ++pt)
#pragma unroll
        for (int jc = 0; jc < 2; ++jc)
          bfr[pt][jc] = BT[(s * 8 + pt * 2 + jc) * 64 + lane];

      // Stage 1: U = X * B_s^T.  D tile (it,pt): lane holds col p=l15, rows i=4g+r.
      f32x4 a1[4][4];
#pragma unroll
      for (int a = 0; a < 4; ++a)
#pragma unroll
        for (int b = 0; b < 4; ++b)
          a1[a][b] = (f32x4){0.f, 0.f, 0.f, 0.f};
#pragma unroll
      for (int it = 0; it < 4; ++it)
#pragma unroll
        for (int pt = 0; pt < 4; ++pt)
#pragma unroll
          for (int jc = 0; jc < 2; ++jc)
            a1[it][pt] = __builtin_amdgcn_mfma_f32_16x16x32_bf16(
                xf[it][jc], bfr[pt][jc], a1[it][pt], 0, 0, 0);

      // Repack U in-lane: stage-2 A-op elem e of chunk c = a1[(e>>2)+2c][pt] reg (e&3).
      bf16x8 uf[4][2];
#pragma unroll
      for (int pt = 0; pt < 4; ++pt)
#pragma unroll
        for (int c = 0; c < 2; ++c) {
          bf16x8 t;
#pragma unroll
          for (int e = 0; e < 8; ++e)
            t[e] = f2bf(a1[(e >> 2) + 2 * c][pt][e & 3]);
          uf[pt][c] = t;
        }

      bf16x8 afr[4][2];
#pragma unroll
      for (int ot = 0; ot < 4; ++ot)
#pragma unroll
        for (int c = 0; c < 2; ++c)
          afr[ot][c] = AT[(s * 8 + ot * 2 + c) * 64 + lane];

      // Stage 2: Y^T tiles. D tile (pt,ot): lane holds col o=l15, rows p=4g+r.
#pragma unroll
      for (int pt = 0; pt < 4; ++pt)
#pragma unroll
        for (int ot = 0; ot < 4; ++ot)
#pragma unroll
          for (int c = 0; c < 2; ++c)
            acc2[pt][ot] = __builtin_amdgcn_mfma_f32_16x16x32_bf16(
                uf[pt][c], afr[ot][c], acc2[pt][ot], 0, 0, 0);
    }

    // ---- store; ot outer / pt inner: each 16-row x 256B band (full 128B
    // lines) completes within 4 consecutive instructions ----
    float* ob = out + (((size_t)(k * NSTREAM + sid)) << 12);
#pragma unroll
    for (int ot = 0; ot < 4; ++ot)
#pragma unroll
      for (int pt = 0; pt < 4; ++pt)
        *(f32x4*)(ob + (ot * 16 + l15) * 64 + pt * 16 + pcol) = acc2[pt][ot];
  }
}

extern "C" void kernel_launch(void* const* d_in, const int* in_sizes, int n_in,
                              void* d_out, int out_size, void* d_ws, size_t ws_size,
                              hipStream_t stream) {
  const float* x    = (const float*)d_in[0];
  const float* A    = (const float*)d_in[1];
  const float* B    = (const float*)d_in[2];
  const float* bias = (const float*)d_in[3];
  float* out        = (float*)d_out;
  kron_kernel<<<dim3(NBLOCK), dim3(256), 0, stream>>>(x, A, B, bias, out);
}

// Round 7
// 104.856 us; speedup vs baseline: 1.0871x; 1.0871x over previous
//
#include <hip/hip_runtime.h>
#include <hip/hip_bf16.h>

typedef float  f32x4  __attribute__((ext_vector_type(4)));
typedef short  bf16x8 __attribute__((ext_vector_type(8)));

#define NT      16384              // BATCH*SEQ tokens
#define NBLOCK  256                // 256 blocks x 4 waves; VGPR>256 -> 1 block/CU
#define WPB     4
#define NSTREAM (NBLOCK * WPB)     // 1024 streams
#define TPS     (NT / NSTREAM)     // 16 tokens per wave, strided by NSTREAM

__device__ __forceinline__ short f2bf(float x) {
  // HW conversion: compiler emits v_cvt_pk_bf16_f32 (RNE).
  return (short)__builtin_bit_cast(unsigned short, __float2bfloat16(x));
}

__global__ __launch_bounds__(256, 1)
void kron_kernel(const float* __restrict__ x,
                 const float* __restrict__ A,
                 const float* __restrict__ Bm,
                 const float* __restrict__ bias,
                 float* __restrict__ out) {
  // Only the operand fragment tables live in LDS (32KB). No X staging:
  // X goes global -> VGPR (coalesced 16B/lane), removing the gload_lds->LDS
  // path and all ds_read traffic from the per-token cost.
  __shared__ bf16x8 AT[1024];   // [s*8+ot*2+c][lane], sigma2 baked
  __shared__ bf16x8 BT[1024];   // [s*8+pt*2+jc][lane], sigma1

  const int tid  = threadIdx.x;
  const int lane = tid & 63;
  const int w    = tid >> 6;
  const int g    = lane >> 4;
  const int l15  = lane & 15;
  const int sid  = blockIdx.x * WPB + w;   // stream id in [0, NSTREAM)

  // ---- one-time: operand tables, built cooperatively (4 rows/wave/table) ----
#pragma unroll
  for (int t = 0; t < 4; ++t) {                  // A: idx = s*8 + ot*2 + c
    const int idx = w * 4 + t;
    const int s = idx >> 3, ot = (idx & 7) >> 1, c = idx & 1;
    const int o = ot * 16 + l15;
    bf16x8 v;
#pragma unroll
    for (int e = 0; e < 8; ++e) {
      const int i = c * 32 + 4 * g + (e & 3) + 16 * (e >> 2);   // sigma2
      v[e] = f2bf(A[s * 4096 + o * 64 + i]);
    }
    AT[idx * 64 + lane] = v;
  }
#pragma unroll
  for (int t = 0; t < 4; ++t) {                  // B: idx = s*8 + pt*2 + jc
    const int idx = w * 4 + t;
    const int s = idx >> 3, pt = (idx & 7) >> 1, jc = idx & 1;
    const int p = pt * 16 + l15;
    bf16x8 v;
#pragma unroll
    for (int e = 0; e < 8; ++e)
      v[e] = f2bf(Bm[s * 4096 + p * 64 + (jc * 32 + 8 * g + e)]); // sigma1
    BT[idx * 64 + lane] = v;
  }

  // ---- bias -> VGPRs (16 x f32x4); acc2 is initialized from these ----
  const int pcol = 4 * g;
  f32x4 bv[4][4];
#pragma unroll
  for (int pt = 0; pt < 4; ++pt)
#pragma unroll
    for (int ot = 0; ot < 4; ++ot)
      bv[pt][ot] = *(const f32x4*)(bias + (ot * 16 + l15) * 64 + pt * 16 + pcol);

  __syncthreads();

  // X fragment loads, straight from global: lane (g,l15) reads rows 16*it+l15,
  // cols 32*jc+8g..+7 (32B = two dwordx4). A wave's 64 lanes tile full rows ->
  // coalesced. Prefetch distance = 1 body (~3-5us >> HBM latency).
  f32x4 xr[4][2][2];               // in-flight fp32 X of the NEXT token (64 VGPR)
  auto loadX = [&](int kk) {
    const float* xb = x + ((size_t)(kk * NSTREAM + sid) << 12);
#pragma unroll
    for (int it = 0; it < 4; ++it)
#pragma unroll
      for (int jc = 0; jc < 2; ++jc) {
        const float* p = xb + (16 * it + l15) * 64 + 32 * jc + 8 * g;
        xr[it][jc][0] = *(const f32x4*)p;
        xr[it][jc][1] = *(const f32x4*)(p + 4);
      }
  };

  bf16x8 xf[4][2];                 // current-token bf16 fragments (32 VGPR)
  auto convX = [&]() {
#pragma unroll
    for (int it = 0; it < 4; ++it)
#pragma unroll
      for (int jc = 0; jc < 2; ++jc) {
        f32x4 f0 = xr[it][jc][0], f1 = xr[it][jc][1];
        bf16x8 t;
        t[0]=f2bf(f0[0]); t[1]=f2bf(f0[1]); t[2]=f2bf(f0[2]); t[3]=f2bf(f0[3]);
        t[4]=f2bf(f1[0]); t[5]=f2bf(f1[1]); t[6]=f2bf(f1[2]); t[7]=f2bf(f1[3]);
        xf[it][jc] = t;
      }
  };

  loadX(0);
  convX();

  for (int k = 0; k < TPS; ++k) {
    // Issue next token's 16 loads first; they drain under ~96 MFMAs + stores.
    if (k + 1 < TPS) loadX(k + 1);
    __builtin_amdgcn_sched_barrier(0);   // pin the loads ahead of the compute

    // ---- acc2 = bias (folded init) ----
    f32x4 acc2[4][4];
#pragma unroll
    for (int pt = 0; pt < 4; ++pt)
#pragma unroll
      for (int ot = 0; ot < 4; ++ot)
        acc2[pt][ot] = bv[pt][ot];

#pragma unroll
    for (int s = 0; s < 2; ++s) {
      bf16x8 bfr[4][2];
#pragma unroll
      for (int pt = 0; pt < 4; ++pt)
#pragma unroll
        for (int jc = 0; jc < 2; ++jc)
          bfr[pt][jc] = BT[(s * 8 + pt * 2 + jc) * 64 + lane];

      // Stage 1: U = X * B_s^T.  D tile (it,pt): lane holds col p=l15, rows i=4g+r.
      f32x4 a1[4][4];
#pragma unroll
      for (int a = 0; a < 4; ++a)
#pragma unroll
        for (int b = 0; b < 4; ++b)
          a1[a][b] = (f32x4){0.f, 0.f, 0.f, 0.f};
#pragma unroll
      for (int it = 0; it < 4; ++it)
#pragma unroll
        for (int pt = 0; pt < 4; ++pt)
#pragma unroll
          for (int jc = 0; jc < 2; ++jc)
            a1[it][pt] = __builtin_amdgcn_mfma_f32_16x16x32_bf16(
                xf[it][jc], bfr[pt][jc], a1[it][pt], 0, 0, 0);

      // Repack U in-lane: stage-2 A-op elem e of chunk c = a1[(e>>2)+2c][pt] reg (e&3).
      bf16x8 uf[4][2];
#pragma unroll
      for (int pt = 0; pt < 4; ++pt)
#pragma unroll
        for (int c = 0; c < 2; ++c) {
          bf16x8 t;
#pragma unroll
          for (int e = 0; e < 8; ++e)
            t[e] = f2bf(a1[(e >> 2) + 2 * c][pt][e & 3]);
          uf[pt][c] = t;
        }

      bf16x8 afr[4][2];
#pragma unroll
      for (int ot = 0; ot < 4; ++ot)
#pragma unroll
        for (int c = 0; c < 2; ++c)
          afr[ot][c] = AT[(s * 8 + ot * 2 + c) * 64 + lane];

      // Stage 2: Y^T tiles. D tile (pt,ot): lane holds col o=l15, rows p=4g+r.
#pragma unroll
      for (int pt = 0; pt < 4; ++pt)
#pragma unroll
        for (int ot = 0; ot < 4; ++ot)
#pragma unroll
          for (int c = 0; c < 2; ++c)
            acc2[pt][ot] = __builtin_amdgcn_mfma_f32_16x16x32_bf16(
                uf[pt][c], afr[ot][c], acc2[pt][ot], 0, 0, 0);
    }

    // ---- non-temporal stores (out is write-once; keep x resident in L3).
    // ot outer / pt inner: each 128B line completed by adjacent instructions.
    float* ob = out + (((size_t)(k * NSTREAM + sid)) << 12);
#pragma unroll
    for (int ot = 0; ot < 4; ++ot)
#pragma unroll
      for (int pt = 0; pt < 4; ++pt)
        __builtin_nontemporal_store(acc2[pt][ot],
            (f32x4*)(ob + (ot * 16 + l15) * 64 + pt * 16 + pcol));

    // Convert next token's X (first and only wait on the xr loads).
    if (k + 1 < TPS) convX();
  }
}

extern "C" void kernel_launch(void* const* d_in, const int* in_sizes, int n_in,
                              void* d_out, int out_size, void* d_ws, size_t ws_size,
                              hipStream_t stream) {
  const float* x    = (const float*)d_in[0];
  const float* A    = (const float*)d_in[1];
  const float* B    = (const float*)d_in[2];
  const float* bias = (const float*)d_in[3];
  float* out        = (float*)d_out;
  kron_kernel<<<dim3(NBLOCK), dim3(256), 0, stream>>>(x, A, B, bias, out);
}

// Round 8
// 104.290 us; speedup vs baseline: 1.0930x; 1.0054x over previous
//
#include <hip/hip_runtime.h>
#include <hip/hip_bf16.h>

typedef float  f32x4  __attribute__((ext_vector_type(4)));
typedef short  bf16x8 __attribute__((ext_vector_type(8)));

#define NT      16384              // BATCH*SEQ tokens
#define NBLOCK  512                // 2 blocks/CU (VGPR 176x2<=512, LDS 32KBx2) -> 2 waves/SIMD
#define WPB     4
#define NSTREAM (NBLOCK * WPB)     // 2048 streams
#define TPS     (NT / NSTREAM)     // 8 tokens per wave, strided by NSTREAM

__device__ __forceinline__ short f2bf(float x) {
  // HW conversion: compiler emits v_cvt_pk_bf16_f32 (RNE).
  return (short)__builtin_bit_cast(unsigned short, __float2bfloat16(x));
}

__global__ __launch_bounds__(256, 1)   // (256,1): known-good 176-VGPR codegen (R7).
void kron_kernel(const float* __restrict__ x,
                 const float* __restrict__ A,
                 const float* __restrict__ Bm,
                 const float* __restrict__ bias,
                 float* __restrict__ out) {
  // Only the operand fragment tables live in LDS (32KB). No X staging:
  // X goes global -> VGPR (coalesced 16B/lane). 2 blocks co-resident per CU
  // give 2 waves/SIMD so one wave's dependency bubbles are filled by the other.
  __shared__ bf16x8 AT[1024];   // [s*8+ot*2+c][lane], sigma2 baked
  __shared__ bf16x8 BT[1024];   // [s*8+pt*2+jc][lane], sigma1

  const int tid  = threadIdx.x;
  const int lane = tid & 63;
  const int w    = tid >> 6;
  const int g    = lane >> 4;
  const int l15  = lane & 15;
  const int sid  = blockIdx.x * WPB + w;   // stream id in [0, NSTREAM)

  // ---- one-time: operand tables, built cooperatively (4 rows/wave/table) ----
#pragma unroll
  for (int t = 0; t < 4; ++t) {                  // A: idx = s*8 + ot*2 + c
    const int idx = w * 4 + t;
    const int s = idx >> 3, ot = (idx & 7) >> 1, c = idx & 1;
    const int o = ot * 16 + l15;
    bf16x8 v;
#pragma unroll
    for (int e = 0; e < 8; ++e) {
      const int i = c * 32 + 4 * g + (e & 3) + 16 * (e >> 2);   // sigma2
      v[e] = f2bf(A[s * 4096 + o * 64 + i]);
    }
    AT[idx * 64 + lane] = v;
  }
#pragma unroll
  for (int t = 0; t < 4; ++t) {                  // B: idx = s*8 + pt*2 + jc
    const int idx = w * 4 + t;
    const int s = idx >> 3, pt = (idx & 7) >> 1, jc = idx & 1;
    const int p = pt * 16 + l15;
    bf16x8 v;
#pragma unroll
    for (int e = 0; e < 8; ++e)
      v[e] = f2bf(Bm[s * 4096 + p * 64 + (jc * 32 + 8 * g + e)]); // sigma1
    BT[idx * 64 + lane] = v;
  }

  // ---- bias -> VGPRs (16 x f32x4); acc2 is initialized from these ----
  const int pcol = 4 * g;
  f32x4 bv[4][4];
#pragma unroll
  for (int pt = 0; pt < 4; ++pt)
#pragma unroll
    for (int ot = 0; ot < 4; ++ot)
      bv[pt][ot] = *(const f32x4*)(bias + (ot * 16 + l15) * 64 + pt * 16 + pcol);

  __syncthreads();

  // X fragment loads, straight from global: lane (g,l15) reads rows 16*it+l15,
  // cols 32*jc+8g..+7 (32B = two dwordx4). A wave's 64 lanes tile full rows ->
  // coalesced. Prefetch distance = 1 body (>> HBM latency).
  f32x4 xr[4][2][2];               // in-flight fp32 X of the NEXT token (64 VGPR)
  auto loadX = [&](int kk) {
    const float* xb = x + ((size_t)(kk * NSTREAM + sid) << 12);
#pragma unroll
    for (int it = 0; it < 4; ++it)
#pragma unroll
      for (int jc = 0; jc < 2; ++jc) {
        const float* p = xb + (16 * it + l15) * 64 + 32 * jc + 8 * g;
        xr[it][jc][0] = *(const f32x4*)p;
        xr[it][jc][1] = *(const f32x4*)(p + 4);
      }
  };

  bf16x8 xf[4][2];                 // current-token bf16 fragments (32 VGPR)
  auto convX = [&]() {
#pragma unroll
    for (int it = 0; it < 4; ++it)
#pragma unroll
      for (int jc = 0; jc < 2; ++jc) {
        f32x4 f0 = xr[it][jc][0], f1 = xr[it][jc][1];
        bf16x8 t;
        t[0]=f2bf(f0[0]); t[1]=f2bf(f0[1]); t[2]=f2bf(f0[2]); t[3]=f2bf(f0[3]);
        t[4]=f2bf(f1[0]); t[5]=f2bf(f1[1]); t[6]=f2bf(f1[2]); t[7]=f2bf(f1[3]);
        xf[it][jc] = t;
      }
  };

  loadX(0);
  convX();

  for (int k = 0; k < TPS; ++k) {
    // Issue next token's 16 loads first; they drain under ~96 MFMAs + stores.
    if (k + 1 < TPS) loadX(k + 1);
    __builtin_amdgcn_sched_barrier(0);   // pin the loads ahead of the compute

    // ---- acc2 = bias (folded init) ----
    f32x4 acc2[4][4];
#pragma unroll
    for (int pt = 0; pt < 4; ++pt)
#pragma unroll
      for (int ot = 0; ot < 4; ++ot)
        acc2[pt][ot] = bv[pt][ot];

#pragma unroll
    for (int s = 0; s < 2; ++s) {
      bf16x8 bfr[4][2];
#pragma unroll
      for (int pt = 0; pt < 4; ++pt)
#pragma unroll
        for (int jc = 0; jc < 2; ++jc)
          bfr[pt][jc] = BT[(s * 8 + pt * 2 + jc) * 64 + lane];

      // Stage 1: U = X * B_s^T.  D tile (it,pt): lane holds col p=l15, rows i=4g+r.
      f32x4 a1[4][4];
#pragma unroll
      for (int a = 0; a < 4; ++a)
#pragma unroll
        for (int b = 0; b < 4; ++b)
          a1[a][b] = (f32x4){0.f, 0.f, 0.f, 0.f};
#pragma unroll
      for (int it = 0; it < 4; ++it)
#pragma unroll
        for (int pt = 0; pt < 4; ++pt)
#pragma unroll
          for (int jc = 0; jc < 2; ++jc)
            a1[it][pt] = __builtin_amdgcn_mfma_f32_16x16x32_bf16(
                xf[it][jc], bfr[pt][jc], a1[it][pt], 0, 0, 0);

      // Repack U in-lane: stage-2 A-op elem e of chunk c = a1[(e>>2)+2c][pt] reg (e&3).
      bf16x8 uf[4][2];
#pragma unroll
      for (int pt = 0; pt < 4; ++pt)
#pragma unroll
        for (int c = 0; c < 2; ++c) {
          bf16x8 t;
#pragma unroll
          for (int e = 0; e < 8; ++e)
            t[e] = f2bf(a1[(e >> 2) + 2 * c][pt][e & 3]);
          uf[pt][c] = t;
        }

      bf16x8 afr[4][2];
#pragma unroll
      for (int ot = 0; ot < 4; ++ot)
#pragma unroll
        for (int c = 0; c < 2; ++c)
          afr[ot][c] = AT[(s * 8 + ot * 2 + c) * 64 + lane];

      // Stage 2: Y^T tiles. D tile (pt,ot): lane holds col o=l15, rows p=4g+r.
#pragma unroll
      for (int pt = 0; pt < 4; ++pt)
#pragma unroll
        for (int ot = 0; ot < 4; ++ot)
#pragma unroll
          for (int c = 0; c < 2; ++c)
            acc2[pt][ot] = __builtin_amdgcn_mfma_f32_16x16x32_bf16(
                uf[pt][c], afr[ot][c], acc2[pt][ot], 0, 0, 0);
    }

    // ---- non-temporal stores (out is write-once; keep x resident in L3).
    // ot outer / pt inner: each 128B line completed by adjacent instructions.
    float* ob = out + (((size_t)(k * NSTREAM + sid)) << 12);
#pragma unroll
    for (int ot = 0; ot < 4; ++ot)
#pragma unroll
      for (int pt = 0; pt < 4; ++pt)
        __builtin_nontemporal_store(acc2[pt][ot],
            (f32x4*)(ob + (ot * 16 + l15) * 64 + pt * 16 + pcol));

    // Convert next token's X (first and only wait on the xr loads).
    if (k + 1 < TPS) convX();
  }
}

extern "C" void kernel_launch(void* const* d_in, const int* in_sizes, int n_in,
                              void* d_out, int out_size, void* d_ws, size_t ws_size,
                              hipStream_t stream) {
  const float* x    = (const float*)d_in[0];
  const float* A    = (const float*)d_in[1];
  const float* B    = (const float*)d_in[2];
  const float* bias = (const float*)d_in[3];
  float* out        = (float*)d_out;
  kron_kernel<<<dim3(NBLOCK), dim3(256), 0, stream>>>(x, A, B, bias, out);
}